// Round 5
// baseline (233.350 us; speedup 1.0000x reference)
//
#include <hip/hip_runtime.h>
#include <hip/hip_bf16.h>

#define IN_F   1024
#define OUT_F  1024
#define TOKENS 8192
#define KTOT   9216
#define NTILE  144          // KTOT / 64; tiles 0..15 silu, 16..143 basis

typedef __attribute__((ext_vector_type(8))) short  bf16x8;
typedef __attribute__((ext_vector_type(4))) float  f32x4;

template<int M> struct ModeT { static constexpr int value = M; };

__device__ __forceinline__ unsigned int f2bf(float f) {
    union { float f; unsigned int u; } v; v.f = f;
    unsigned int r = v.u + 0x7fffu + ((v.u >> 16) & 1u);
    return r >> 16;
}

// silu(x) -> siluA [8192][1024] bf16. One thread per 8 elements.
__global__ __launch_bounds__(256)
void prep_a_lite(const float* __restrict__ x, unsigned short* __restrict__ siluA)
{
    int idx = blockIdx.x * blockDim.x + threadIdx.x;   // 1,048,576 threads
    const float4* s = reinterpret_cast<const float4*>(x + (size_t)idx * 8);
    float4 lo = s[0], hi = s[1];
    float v[8] = {lo.x, lo.y, lo.z, lo.w, hi.x, hi.y, hi.z, hi.w};
    unsigned int h[8];
    #pragma unroll
    for (int j = 0; j < 8; ++j)
        h[j] = f2bf(v[j] / (1.0f + __expf(-v[j])));
    uint4 pk;
    pk.x = h[0] | (h[1] << 16);  pk.y = h[2] | (h[3] << 16);
    pk.z = h[4] | (h[5] << 16);  pk.w = h[6] | (h[7] << 16);
    reinterpret_cast<uint4*>(siluA)[idx] = pk;
}

// Repack W [O,1024] and spline [O,1024,8] into bf16 B [O, 9216].
__global__ __launch_bounds__(256)
void prep_b_kernel(const float* __restrict__ W, const float* __restrict__ spl,
                   unsigned short* __restrict__ B)
{
    int idx = blockIdx.x * blockDim.x + threadIdx.x;
    int o  = idx / (KTOT / 8);
    int c8 = idx - o * (KTOT / 8);
    const float* src = (c8 < IN_F / 8)
        ? (W   + (size_t)o * IN_F     + (size_t)c8 * 8)
        : (spl + (size_t)o * IN_F * 8 + (size_t)(c8 - IN_F / 8) * 8);
    const float4* s4 = reinterpret_cast<const float4*>(src);
    float4 lo = s4[0], hi = s4[1];
    uint4 pk;
    pk.x = f2bf(lo.x) | (f2bf(lo.y) << 16);
    pk.y = f2bf(lo.z) | (f2bf(lo.w) << 16);
    pk.z = f2bf(hi.x) | (f2bf(hi.y) << 16);
    pk.w = f2bf(hi.z) | (f2bf(hi.w) << 16);
    *reinterpret_cast<uint4*>(&B[(size_t)o * KTOT + (size_t)c8 * 8]) = pk;
}

// ---------------------------------------------------------------------------
// Fused KAN GEMM: C[8192,1024] = A @ B^T + bias, where A's basis region
// (k>=1024) is computed ON THE FLY from x (4x amplification: 8KB x -> 32KB A
// per tile), silu region (k<1024) staged from materialized siluA.
// Tile 256x128, BK=64, 8 waves (2M x 4N, per-wave 128x32), NO split-K.
// 2 phases/tile, 16 MFMA each. XOR-swizzled LDS; basis A ds_written swizzled.
// Grid: bid&31 = bm (same-XCD blocks share x/siluA slice), bid>>5 = bn.
// ---------------------------------------------------------------------------
#define GLOAD(src, dst) __builtin_amdgcn_global_load_lds( \
    (const __attribute__((address_space(1))) void*)(src),  \
    (__attribute__((address_space(3))) void*)(dst), 16, 0, 0)
#define SBAR()  __builtin_amdgcn_s_barrier()
#define SCH0()  __builtin_amdgcn_sched_barrier(0)
#define LGKM0() asm volatile("s_waitcnt lgkmcnt(0)" ::: "memory")
#define VMC0()  asm volatile("s_waitcnt vmcnt(0)" ::: "memory")

__global__ __launch_bounds__(512, 2)
void gemm_kan3(const float* __restrict__ x,
               const unsigned short* __restrict__ siluA,
               const unsigned short* __restrict__ Bw,
               const float* __restrict__ grid,
               const float* __restrict__ bias,
               float* __restrict__ out)
{
    __shared__ uint4 lds4[98304 / 16];   // A dbuf 64K + B dbuf 32K
    char* lds = (char*)lds4;

    const int bid  = blockIdx.x;
    const int bm   = bid & 31;
    const int bn   = bid >> 5;
    const int tid  = threadIdx.x;
    const int wave = tid >> 6, lane = tid & 63;
    const int wr   = wave >> 2, wc = wave & 3;
    const int fr   = lane & 15, kg = lane >> 4;
    const int sw   = fr & 7;
    const int koff[2] = { (kg ^ sw) * 16, ((4 | kg) ^ sw) * 16 };

    // basis constants: exp(-((x-g)*invd)^2) = 2^(-(x*invd2 - g*invd2)^2)
    const float invd  = 1.0f / (2.0f / 7.0f + 1e-5f);
    const float invd2 = invd * 1.2011224087864498f;    // invd * sqrt(log2 e)
    float ng2[8];
    #pragma unroll
    for (int g = 0; g < 8; ++g) ng2[g] = -grid[g] * invd2;

    // staging pointers
    const int trow = tid >> 3;
    const int gsw  = ((tid & 7) ^ (trow & 7)) * 8;     // inverse-swizzled granule
    const unsigned short* gS = siluA + (size_t)(bm * 256 + trow) * 1024 + gsw;
    const unsigned short* gB = Bw    + (size_t)(bn * 128 + trow) * 9216 + gsw;
    const float*          xg = x     + (size_t)(bm * 256 + (tid >> 1)) * 1024
                                     + (tid & 1) * 4;
    const size_t R64S = (size_t)64 * 1024;
    const size_t R64B = (size_t)64 * 9216;

    f32x4 acc[8][2];
    const f32x4 zero = {0.f, 0.f, 0.f, 0.f};
    #pragma unroll
    for (int m = 0; m < 8; ++m) { acc[m][0] = zero; acc[m][1] = zero; }

    // prologue: stage tile 0 (silu) -> buf0
    {
        char* d = lds + tid * 16;
        GLOAD(gS,            d);
        GLOAD(gS + R64S,     d + 8192);
        GLOAD(gS + 2 * R64S, d + 16384);
        GLOAD(gS + 3 * R64S, d + 24576);
        GLOAD(gB,            d + 65536);
        GLOAD(gB + R64B,     d + 65536 + 8192);
        gS += 64; gB += 64;
    }
    VMC0(); SBAR(); SCH0();

    const int aOff = (wr * 128 + fr) * 128;   // + mi*2048 (+8192 for hi half)
    const int bOff = (wc * 32 + fr) * 128;    // + ni*2048

    bf16x8 af[4][2], bf[2][2];
    int u = 0;

    // NEXT: 0 = silu tile next (gload siluA), 1 = basis next (compute), 2 = none
    auto tile = [&](auto mC) {
        constexpr int NEXT = decltype(mC)::value;
        char* bufA = lds + (u & 1) * 32768;
        char* bufB = lds + 65536 + (u & 1) * 16384;
        char* dAn  = lds + ((u + 1) & 1) * 32768 + tid * 16;
        char* dBn  = lds + 65536 + ((u + 1) & 1) * 16384 + tid * 16;

        // ---- phase 1: A-lo + B frags; issue next-tile staging ----
        #pragma unroll
        for (int mi = 0; mi < 4; ++mi)
            #pragma unroll
            for (int ks = 0; ks < 2; ++ks)
                af[mi][ks] = *(const bf16x8*)(bufA + aOff + mi * 2048 + koff[ks]);
        #pragma unroll
        for (int ni = 0; ni < 2; ++ni)
            #pragma unroll
            for (int ks = 0; ks < 2; ++ks)
                bf[ni][ks] = *(const bf16x8*)(bufB + bOff + ni * 2048 + koff[ks]);
        float4 xq = {0.f, 0.f, 0.f, 0.f};
        if constexpr (NEXT == 0) {
            GLOAD(gS,            dAn);
            GLOAD(gS + R64S,     dAn + 8192);
            GLOAD(gS + 2 * R64S, dAn + 16384);
            GLOAD(gS + 3 * R64S, dAn + 24576);
        }
        if constexpr (NEXT == 1) {
            xq = *reinterpret_cast<const float4*>(xg);   // reg-staged x
        }
        if constexpr (NEXT <= 1) {
            GLOAD(gB,        dBn);
            GLOAD(gB + R64B, dBn + 8192);
        }
        SBAR(); SCH0(); LGKM0(); SCH0();
        __builtin_amdgcn_s_setprio(1);
        #pragma unroll
        for (int mi = 0; mi < 4; ++mi)
            #pragma unroll
            for (int ni = 0; ni < 2; ++ni)
                #pragma unroll
                for (int ks = 0; ks < 2; ++ks)
                    acc[mi][ni] = __builtin_amdgcn_mfma_f32_16x16x32_bf16(
                        af[mi][ks], bf[ni][ks], acc[mi][ni], 0, 0, 0);
        __builtin_amdgcn_s_setprio(0);
        SBAR(); SCH0();

        // ---- phase 2: A-hi frags; MFMA + (basis-compute for tile u+1) ----
        #pragma unroll
        for (int mi = 0; mi < 4; ++mi)
            #pragma unroll
            for (int ks = 0; ks < 2; ++ks)
                af[mi][ks] = *(const bf16x8*)(bufA + aOff + 8192 + mi * 2048 + koff[ks]);
        SBAR(); SCH0(); LGKM0(); SCH0();
        __builtin_amdgcn_s_setprio(1);
        #pragma unroll
        for (int mi = 0; mi < 4; ++mi)
            #pragma unroll
            for (int ni = 0; ni < 2; ++ni)
                #pragma unroll
                for (int ks = 0; ks < 2; ++ks)
                    acc[4 + mi][ni] = __builtin_amdgcn_mfma_f32_16x16x32_bf16(
                        af[mi][ks], bf[ni][ks], acc[4 + mi][ni], 0, 0, 0);
        __builtin_amdgcn_s_setprio(0);
        if constexpr (NEXT == 1) {
            // compute basis A[u+1]: this thread owns row r = tid>>1,
            // granules i = 4*(tid&1)+q  (q=0..3), 8 g-values each.
            const int   r   = tid >> 1;
            const int   ib  = 4 * (tid & 1);
            char* wbase = lds + ((u + 1) & 1) * 32768 + r * 128;
            float xa[4] = {xq.x, xq.y, xq.z, xq.w};
            #pragma unroll
            for (int q = 0; q < 4; ++q) {
                float e[8];
                #pragma unroll
                for (int g = 0; g < 8; ++g) {
                    float t = fmaf(xa[q], invd2, ng2[g]);
                    float a = -t * t;
                    asm("v_exp_f32 %0, %1" : "=v"(e[g]) : "v"(a));
                }
                unsigned int pk[4];
                #pragma unroll
                for (int p = 0; p < 4; ++p) {
                    __hip_bfloat162 h =
                        __float22bfloat162_rn(float2{e[2 * p], e[2 * p + 1]});
                    pk[p] = *reinterpret_cast<unsigned int*>(&h);
                }
                *reinterpret_cast<uint4*>(
                    wbase + (((ib + q) ^ (r & 7)) * 16)) =
                    make_uint4(pk[0], pk[1], pk[2], pk[3]);
            }
        }
        if constexpr (NEXT <= 1) {
            LGKM0();        // basis ds_writes drained (and phase-2 reads)
            VMC0();         // next-tile gloads resident
        }
        SCH0(); SBAR(); SCH0();

        if constexpr (NEXT == 0) { gS += 64; gB += 64; }
        if constexpr (NEXT == 1) { xg += 8;  gB += 64; }
    };

    for (u = 0; u < 15; ++u)     tile(ModeT<0>{});   // stages silu tiles 1..15
    for (; u < NTILE - 1; ++u)   tile(ModeT<1>{});   // stages basis tiles 16..143
    tile(ModeT<2>{});                                 // last tile, no staging

    // epilogue: direct C write + bias
    const size_t orow0 = (size_t)bm * 256 + (size_t)wr * 128;
    const int    ocol0 = bn * 128 + wc * 32;
    #pragma unroll
    for (int n = 0; n < 2; ++n) {
        const int col = ocol0 + n * 16 + fr;
        const float bv = bias[col];
        #pragma unroll
        for (int m = 0; m < 8; ++m) {
            const size_t r0 = orow0 + (m >> 2) * 64 + (m & 3) * 16 + kg * 4;
            #pragma unroll
            for (int j = 0; j < 4; ++j)
                out[(r0 + j) * OUT_F + col] = acc[m][n][j] + bv;
        }
    }
}

extern "C" void kernel_launch(void* const* d_in, const int* in_sizes, int n_in,
                              void* d_out, int out_size, void* d_ws, size_t ws_size,
                              hipStream_t stream)
{
    const float* x    = (const float*)d_in[0];
    const float* W    = (const float*)d_in[1];
    const float* bias = (const float*)d_in[2];
    const float* spl  = (const float*)d_in[3];
    const float* grid = (const float*)d_in[4];
    float* out = (float*)d_out;

    unsigned short* Bw    = (unsigned short*)d_ws;             // 18.9 MB
    unsigned short* siluA = Bw + (size_t)OUT_F * KTOT;         // 16.8 MB

    prep_b_kernel<<<(OUT_F * (KTOT / 8)) / 256, 256, 0, stream>>>(W, spl, Bw);
    prep_a_lite<<<(TOKENS * IN_F / 8) / 256, 256, 0, stream>>>(x, siluA);
    gemm_kan3<<<256, 512, 0, stream>>>(x, siluA, Bw, grid, bias, out);
}

// Round 6
// 195.169 us; speedup vs baseline: 1.1956x; 1.1956x over previous
//
#include <hip/hip_runtime.h>
#include <hip/hip_bf16.h>

#define IN_F   1024
#define OUT_F  1024
#define TOKENS 8192
#define KTOT   9216
#define KHALF  4608
#define NTILE  72          // KHALF / 64

typedef __attribute__((ext_vector_type(8))) short  bf16x8;
typedef __attribute__((ext_vector_type(4))) float  f32x4;

template<int M> struct ModeT { static constexpr int value = M; };

__device__ __forceinline__ unsigned int f2bf(float f) {
    union { float f; unsigned int u; } v; v.f = f;
    unsigned int r = v.u + 0x7fffu + ((v.u >> 16) & 1u);
    return r >> 16;
}

// One thread per (t, i): silu(x) -> A[t][i]; 8 RBF basis -> A[t][1024+i*8..] (16B store)
__global__ __launch_bounds__(256)
void prep_a_kernel(const float* __restrict__ x, const float* __restrict__ grid,
                   unsigned short* __restrict__ A)
{
    int idx = blockIdx.x * blockDim.x + threadIdx.x;
    int t = idx >> 10;
    int i = idx & 1023;
    float xv = x[idx];
    float sil = xv / (1.0f + __expf(-xv));
    A[(size_t)t * KTOT + i] = (unsigned short)f2bf(sil);

    const float invd = 1.0f / (2.0f / 7.0f + 1e-5f);
    unsigned int h[8];
    #pragma unroll
    for (int g = 0; g < 8; ++g) {
        float d = (xv - grid[g]) * invd;
        h[g] = f2bf(__expf(-d * d));
    }
    uint4 pk;
    pk.x = h[0] | (h[1] << 16);
    pk.y = h[2] | (h[3] << 16);
    pk.z = h[4] | (h[5] << 16);
    pk.w = h[6] | (h[7] << 16);
    *reinterpret_cast<uint4*>(&A[(size_t)t * KTOT + IN_F + (size_t)i * 8]) = pk;
}

// Repack W [O,1024] and spline [O,1024,8] into bf16 B [O, 9216].
__global__ __launch_bounds__(256)
void prep_b_kernel(const float* __restrict__ W, const float* __restrict__ spl,
                   unsigned short* __restrict__ B)
{
    int idx = blockIdx.x * blockDim.x + threadIdx.x;
    int o  = idx / (KTOT / 8);
    int c8 = idx - o * (KTOT / 8);
    const float* src = (c8 < IN_F / 8)
        ? (W   + (size_t)o * IN_F     + (size_t)c8 * 8)
        : (spl + (size_t)o * IN_F * 8 + (size_t)(c8 - IN_F / 8) * 8);
    const float4* s4 = reinterpret_cast<const float4*>(src);
    float4 lo = s4[0], hi = s4[1];
    uint4 pk;
    pk.x = f2bf(lo.x) | (f2bf(lo.y) << 16);
    pk.y = f2bf(lo.z) | (f2bf(lo.w) << 16);
    pk.z = f2bf(hi.x) | (f2bf(hi.y) << 16);
    pk.w = f2bf(hi.z) | (f2bf(hi.w) << 16);
    *reinterpret_cast<uint4*>(&B[(size_t)o * KTOT + (size_t)c8 * 8]) = pk;
}

// ---------------------------------------------------------------------------
// 256x256 tile, BK=64, 8 waves (2M x 4N), split-K=2.
// BARRIER-MINIMAL tile: one s_barrier + one vmcnt(0) per K-tile, 64 MFMA
// between barriers. The 2 waves/SIMD skew freely inside the tile, so LDS
// reads (~1920 cy/CU/tile) hide under matrix-pipe time (~2048 cy/SIMD/tile).
// Clean LDS double-buffer: A bufs [0,64K), B bufs [64K,128K); staging only
// ever writes buf(u+1), reads only from buf(u) -> no interior barrier needed.
//   A row(mi) = wr*64 + (mi&3)*16 + (mi>>2)*128
//   B col(ni) = wc*32 + (ni&1)*16 + (ni>>1)*128
// Quadrant order: q00 (af-lo,bfLo) q01 (af-lo,bfHi) q10 (af-hi,bfLo) q11.
// ---------------------------------------------------------------------------
#define GLOAD(src, dst) __builtin_amdgcn_global_load_lds( \
    (const __attribute__((address_space(1))) void*)(src),  \
    (__attribute__((address_space(3))) void*)(dst), 16, 0, 0)
#define SBAR()  __builtin_amdgcn_s_barrier()
#define SCH0()  __builtin_amdgcn_sched_barrier(0)
#define VMC0()  asm volatile("s_waitcnt vmcnt(0)" ::: "memory")

__global__ __launch_bounds__(512, 2)
void gemm_kan2(const unsigned short* __restrict__ A,
               const unsigned short* __restrict__ B,
               float* __restrict__ P, int rows)
{
    __shared__ char lds[131072];   // A dbuf [0,64K), B dbuf [64K,128K)

    const int bid  = blockIdx.x;
    const int sk   = bid & 1;            // XCD = bid&7 owns one (bn,sk) pair:
    const int bn   = (bid >> 1) & 3;     // its 2.36 MB B-panel stays in its L2
    const int bm   = bid >> 3;
    const int tid  = threadIdx.x;
    const int wave = tid >> 6, lane = tid & 63;
    const int wr   = wave >> 2, wc = wave & 3;
    const int fr   = lane & 15, kg = lane >> 4;
    const int sw   = fr & 7;
    const int koff[2] = { (kg ^ sw) * 16, ((4 | kg) ^ sw) * 16 };
    const int k0 = sk * KHALF;

    // staging: thread covers row (tid>>3), 16B chunk (tid&7), inverse-swizzled k
    const int trow = tid >> 3;
    const int ksrc = ((tid & 7) ^ (trow & 7)) * 8;
    const unsigned short* gA = A + (size_t)(bm * 256 + trow) * KTOT + k0 + ksrc;
    const unsigned short* gB = B + (size_t)(bn * 256 + trow) * KTOT + k0 + ksrc;
    const size_t R64 = (size_t)64 * KTOT;

    f32x4 acc[8][4];
    const f32x4 zero = {0.f, 0.f, 0.f, 0.f};
    #pragma unroll
    for (int m = 0; m < 8; ++m)
        #pragma unroll
        for (int n = 0; n < 4; ++n) acc[m][n] = zero;

    // prologue: stage tile 0 -> buf0 (A units r=0..3, B units r=0..3)
    {
        char* dA = lds + tid * 16;
        char* dB = lds + 65536 + tid * 16;
        GLOAD(gA,           dA);           GLOAD(gA + R64,     dA + 8192);
        GLOAD(gA + 2 * R64, dA + 16384);   GLOAD(gA + 3 * R64, dA + 24576);
        GLOAD(gB,           dB);           GLOAD(gB + R64,     dB + 8192);
        GLOAD(gB + 2 * R64, dB + 16384);   GLOAD(gB + 3 * R64, dB + 24576);
        gA += 64; gB += 64;
    }
    VMC0(); SBAR(); SCH0();

    const int aOff = (wr * 64 + fr) * 128;   // + (mi&3)*2048; +16384 for hi half
    const int bOff = (wc * 32 + fr) * 128;   // + (ni&1)*2048; +16384 for hi half

    bf16x8 af[4][2], bfLo[2][2], bfHi[2][2];
    int u = 0;

    // MODE: 0 = steady (stages tile u+1), 1 = last tile (no staging)
    auto tile = [&](auto mC) {
        constexpr int MODE = decltype(mC)::value;
        char* bufA = lds + (u & 1) * 32768;
        char* bufB = lds + 65536 + (u & 1) * 32768;

        // ---- reads: af-lo, bfLo, bfHi (16 x ds_read_b128) ----
        #pragma unroll
        for (int mi = 0; mi < 4; ++mi)
            #pragma unroll
            for (int ks = 0; ks < 2; ++ks)
                af[mi][ks] = *(const bf16x8*)(bufA + aOff + mi * 2048 + koff[ks]);
        #pragma unroll
        for (int ni = 0; ni < 2; ++ni)
            #pragma unroll
            for (int ks = 0; ks < 2; ++ks) {
                bfLo[ni][ks] = *(const bf16x8*)(bufB + bOff + ni * 2048 + koff[ks]);
                bfHi[ni][ks] = *(const bf16x8*)(bufB + bOff + 16384 + ni * 2048 + koff[ks]);
            }

        // ---- stage tile u+1 into the other buffers ----
        if constexpr (MODE == 0) {
            char* dA = lds + ((u & 1) ^ 1) * 32768 + tid * 16;
            char* dB = lds + 65536 + ((u & 1) ^ 1) * 32768 + tid * 16;
            GLOAD(gA,           dA);           GLOAD(gA + R64,     dA + 8192);
            GLOAD(gA + 2 * R64, dA + 16384);   GLOAD(gA + 3 * R64, dA + 24576);
            GLOAD(gB,           dB);           GLOAD(gB + R64,     dB + 8192);
            GLOAD(gB + 2 * R64, dB + 16384);   GLOAD(gB + 3 * R64, dB + 24576);
            gA += 64; gB += 64;
        }
        SCH0();

        // ---- q00: af-lo x bfLo ----
        __builtin_amdgcn_s_setprio(1);
        #pragma unroll
        for (int mi = 0; mi < 4; ++mi)
            #pragma unroll
            for (int ni = 0; ni < 2; ++ni)
                #pragma unroll
                for (int ks = 0; ks < 2; ++ks)
                    acc[mi][ni] = __builtin_amdgcn_mfma_f32_16x16x32_bf16(
                        af[mi][ks], bfLo[ni][ks], acc[mi][ni], 0, 0, 0);
        __builtin_amdgcn_s_setprio(0);

        // ---- q01: af-lo x bfHi ----
        __builtin_amdgcn_s_setprio(1);
        #pragma unroll
        for (int mi = 0; mi < 4; ++mi)
            #pragma unroll
            for (int ni = 0; ni < 2; ++ni)
                #pragma unroll
                for (int ks = 0; ks < 2; ++ks)
                    acc[mi][2 + ni] = __builtin_amdgcn_mfma_f32_16x16x32_bf16(
                        af[mi][ks], bfHi[ni][ks], acc[mi][2 + ni], 0, 0, 0);
        __builtin_amdgcn_s_setprio(0);

        // ---- af-hi reads (8 x ds_read_b128), overlap q01 drain ----
        #pragma unroll
        for (int mi = 0; mi < 4; ++mi)
            #pragma unroll
            for (int ks = 0; ks < 2; ++ks)
                af[mi][ks] = *(const bf16x8*)(bufA + aOff + 16384 + mi * 2048 + koff[ks]);

        // ---- q10: af-hi x bfLo ----
        __builtin_amdgcn_s_setprio(1);
        #pragma unroll
        for (int mi = 0; mi < 4; ++mi)
            #pragma unroll
            for (int ni = 0; ni < 2; ++ni)
                #pragma unroll
                for (int ks = 0; ks < 2; ++ks)
                    acc[4 + mi][ni] = __builtin_amdgcn_mfma_f32_16x16x32_bf16(
                        af[mi][ks], bfLo[ni][ks], acc[4 + mi][ni], 0, 0, 0);
        __builtin_amdgcn_s_setprio(0);

        // ---- q11: af-hi x bfHi ----
        __builtin_amdgcn_s_setprio(1);
        #pragma unroll
        for (int mi = 0; mi < 4; ++mi)
            #pragma unroll
            for (int ni = 0; ni < 2; ++ni)
                #pragma unroll
                for (int ks = 0; ks < 2; ++ks)
                    acc[4 + mi][2 + ni] = __builtin_amdgcn_mfma_f32_16x16x32_bf16(
                        af[mi][ks], bfHi[ni][ks], acc[4 + mi][2 + ni], 0, 0, 0);
        __builtin_amdgcn_s_setprio(0);

        SCH0();
        if constexpr (MODE == 0) {
            VMC0();          // tile u+1 resident
            SBAR(); SCH0();  // all waves done reading buf(u); safe to overwrite next
        }
    };

    for (u = 0; u < NTILE - 1; ++u) tile(ModeT<0>{});
    tile(ModeT<1>{});

    // epilogue: write f32 partials (interleaved-quadrant mapping)
    float* Pp = P + (size_t)sk * rows * OUT_F;
    const size_t orow0 = (size_t)bm * 256 + (size_t)wr * 64;
    const int    ocol0 = bn * 256 + wc * 32;
    #pragma unroll
    for (int n = 0; n < 4; ++n) {
        const int col = ocol0 + (n & 1) * 16 + (n >> 1) * 128 + fr;
        #pragma unroll
        for (int m = 0; m < 8; ++m) {
            const size_t r0 = orow0 + (m & 3) * 16 + (m >> 2) * 128 + kg * 4;
            #pragma unroll
            for (int j = 0; j < 4; ++j)
                Pp[(r0 + j) * OUT_F + col] = acc[m][n][j];
        }
    }
}

// out = P0 + P1 + bias
__global__ __launch_bounds__(256)
void reduce_kan(const float* __restrict__ P, const float* __restrict__ bias,
                float* __restrict__ out, int n4, int skStride4)
{
    const float4* p0 = (const float4*)P;
    const float4* p1 = p0 + skStride4;
    const float4* bv = (const float4*)bias;
    float4* o = (float4*)out;
    for (int i = blockIdx.x * blockDim.x + threadIdx.x; i < n4;
         i += gridDim.x * blockDim.x) {
        float4 a = p0[i], b = p1[i], c = bv[i & 255];
        float4 r;
        r.x = a.x + b.x + c.x;  r.y = a.y + b.y + c.y;
        r.z = a.z + b.z + c.z;  r.w = a.w + b.w + c.w;
        o[i] = r;
    }
}

extern "C" void kernel_launch(void* const* d_in, const int* in_sizes, int n_in,
                              void* d_out, int out_size, void* d_ws, size_t ws_size,
                              hipStream_t stream)
{
    const float* x    = (const float*)d_in[0];
    const float* W    = (const float*)d_in[1];
    const float* bias = (const float*)d_in[2];
    const float* spl  = (const float*)d_in[3];
    const float* grid = (const float*)d_in[4];
    float* out = (float*)d_out;

    unsigned short* Bw = (unsigned short*)d_ws;               // 18.9 MB
    unsigned short* Aw = Bw + (size_t)OUT_F * KTOT;

    // per-row ws: A bf16 (18432 B) + 2x f32 partial (8192 B)
    const size_t bBytes = (size_t)OUT_F * KTOT * 2;
    size_t avail = ws_size > bBytes ? ws_size - bBytes : 0;
    long maxRows = (long)(avail / 26624);
    int chunk = (maxRows >= TOKENS) ? TOKENS : (int)((maxRows / 256) * 256);
    if (chunk < 256) chunk = 256;
    float* Pp = (float*)(Aw + (size_t)chunk * KTOT);

    prep_b_kernel<<<(OUT_F * (KTOT / 8)) / 256, 256, 0, stream>>>(W, spl, Bw);

    for (int t0 = 0; t0 < TOKENS; t0 += chunk) {
        int rows = (TOKENS - t0 < chunk) ? (TOKENS - t0) : chunk;
        prep_a_kernel<<<(rows * IN_F) / 256, 256, 0, stream>>>(
            x + (size_t)t0 * IN_F, grid, Aw);
        gemm_kan2<<<(rows >> 8) * 8, 512, 0, stream>>>(Aw, Bw, Pp, rows);
        int n4 = rows * 256;
        int rblocks = (n4 + 255) / 256; if (rblocks > 2048) rblocks = 2048;
        reduce_kan<<<rblocks, 256, 0, stream>>>(
            Pp, bias, out + (size_t)t0 * OUT_F, n4, n4);
    }
}